// Round 5
// baseline (725.689 us; speedup 1.0000x reference)
//
#include <hip/hip_runtime.h>
#include <math.h>

// Problem constants (from reference)
#define N_NODES 50000
#define N_EDGES 800000
#define IN_DIM  192      // 2*O + ED
#define BN_EPS  1e-5f

// Workspace layout (4-byte word offsets):
//   P1p    [N,64]  uint @ 0          packed bf16x2 {chan n, chan n+64} of n_feat@W1^T
//   P2p    [N,64]  uint @ 3,200,000  same for W2^T
//   agg    [N,64]  f32  @ 6,400,000
//   stats  [1024]  f32  @ 9,600,000  stats1[256], ss1[256], stats2[128], ss2[128]
//   rows   [N+1]   int  @ 9,601,024  CSR row_start (padded to 50008)
//   cursor [N]     int  @ 9,651,032  histogram counts, then scatter cursors
//   bsums  [256]   int  @ 9,701,040  scan block sums
//   perm   [E]     int  @ 9,701,296  dst-sorted edge ids
//   hbuf   [E,64]  uint @ 10,501,296 packed bf16x2 {filt,core} per chan
#define OFF_P2P    3200000
#define OFF_AGG    6400000
#define OFF_STATS1 9600000
#define OFF_ROWS   9601024
#define OFF_CURSOR 9651032
#define OFF_BSUMS  9701040
#define OFF_PERM   9701296
#define OFF_HBUF   10501296
#define WS_WORDS_NEEDED (OFF_HBUF + (size_t)N_EDGES * 64)
#define SCAN_BLOCKS ((N_NODES + 255) / 256)   // 196

typedef __bf16 bf16x8 __attribute__((ext_vector_type(8)));
typedef __bf16 bf16x2 __attribute__((ext_vector_type(2)));
typedef float  f32x4  __attribute__((ext_vector_type(4)));

__device__ __forceinline__ unsigned pack_bf16x2(float lo, float hi) {
  union { bf16x2 v; unsigned u; } pk;
  pk.v[0] = (__bf16)lo; pk.v[1] = (__bf16)hi;
  return pk.u;
}
// fast transcendentals (native v_exp/v_log/v_rcp)
__device__ __forceinline__ float fast_sigmoid(float f) {
  return __builtin_amdgcn_rcpf(1.f + __expf(-f));
}
__device__ __forceinline__ float fast_softplus(float g) {
  return fmaxf(g, 0.f) + __logf(1.f + __expf(-fabsf(g)));
}
__device__ __forceinline__ float msg_from_pack(unsigned p, float sc_f, float sh_f,
                                               float sc_g, float sh_g) {
  float f = __uint_as_float(p << 16)         * sc_f + sh_f;
  float g = __uint_as_float(p & 0xffff0000u) * sc_g + sh_g;
  return fast_sigmoid(f) * fast_softplus(g);
}

// ---------------------------------------------------------------------------
// Kernel 1: P1p[n][o] = pack(bf16(n_feat[n]·W[o][0:64]), bf16(n_feat[n]·W[o+64][0:64]))
//           P2p same with k-range 64:128.
__global__ __launch_bounds__(256) void k_precompute(
    const float* __restrict__ n_feat, const float* __restrict__ W,
    unsigned* __restrict__ P1p, unsigned* __restrict__ P2p) {
  const int tid = threadIdx.x;
  const int o   = tid & 63;
  const int sel = tid >> 6;                 // 0..3
  const int ch  = o + (sel & 1) * 64;
  const int kb  = (sel & 2) ? 64 : 0;
  float4 wreg[16];
  const float* wrow = W + (size_t)ch * IN_DIM + kb;
#pragma unroll
  for (int i = 0; i < 16; ++i) wreg[i] = *(const float4*)(wrow + i * 4);
  __shared__ float xrow[4][64];
  __shared__ float accbuf[4][4][64];        // [sel][r][o]
  for (int r0 = blockIdx.x * 4; r0 < N_NODES; r0 += gridDim.x * 4) {
    xrow[tid >> 6][tid & 63] = n_feat[(size_t)(r0 + (tid >> 6)) * 64 + (tid & 63)];
    __syncthreads();
    float acc[4] = {0.f, 0.f, 0.f, 0.f};
#pragma unroll
    for (int kk = 0; kk < 16; ++kk) {
      float4 wv = wreg[kk];
#pragma unroll
      for (int r = 0; r < 4; ++r) {
        float4 xv = *(const float4*)&xrow[r][kk * 4];
        acc[r] += wv.x * xv.x + wv.y * xv.y + wv.z * xv.z + wv.w * xv.w;
      }
    }
#pragma unroll
    for (int r = 0; r < 4; ++r) accbuf[sel][r][o] = acc[r];
    __syncthreads();
    const size_t rr = (size_t)(r0 + sel) * 64 + o;
    P1p[rr] = pack_bf16x2(accbuf[0][sel][o], accbuf[1][sel][o]);
    P2p[rr] = pack_bf16x2(accbuf[2][sel][o], accbuf[3][sel][o]);
    __syncthreads();
  }
}

// ---------------------------------------------------------------------------
// CSR build: histogram -> exclusive scan (3 kernels) -> scatter permutation.
__global__ __launch_bounds__(256) void k_hist(const int* __restrict__ dst,
                                              int* __restrict__ counts) {
  int e = blockIdx.x * 256 + threadIdx.x;
  if (e < N_EDGES) atomicAdd(&counts[dst[e]], 1);
}

__global__ __launch_bounds__(256) void k_scan1(const int* __restrict__ counts,
                                               int* __restrict__ bsums) {
  __shared__ int red[256];
  int i = blockIdx.x * 256 + threadIdx.x;
  red[threadIdx.x] = (i < N_NODES) ? counts[i] : 0;
  __syncthreads();
  for (int s = 128; s > 0; s >>= 1) {
    if (threadIdx.x < s) red[threadIdx.x] += red[threadIdx.x + s];
    __syncthreads();
  }
  if (threadIdx.x == 0) bsums[blockIdx.x] = red[0];
}

__global__ __launch_bounds__(256) void k_scan2(int* __restrict__ bsums) {
  __shared__ int a[256], b[256];
  int t = threadIdx.x;
  int v = (t < SCAN_BLOCKS) ? bsums[t] : 0;
  int* cur = a; int* nxt = b;
  cur[t] = v; __syncthreads();
  for (int off = 1; off < 256; off <<= 1) {
    nxt[t] = cur[t] + ((t >= off) ? cur[t - off] : 0);
    __syncthreads();
    int* tmp = cur; cur = nxt; nxt = tmp;
  }
  if (t < SCAN_BLOCKS) bsums[t] = cur[t] - v;   // exclusive
}

__global__ __launch_bounds__(256) void k_scan3(const int* __restrict__ bsums,
                                               int* __restrict__ row_start,
                                               int* __restrict__ cursor) {
  __shared__ int a[256], b[256];
  int i = blockIdx.x * 256 + threadIdx.x;
  int t = threadIdx.x;
  int v = (i < N_NODES) ? cursor[i] : 0;        // cursor currently holds counts
  int* cur = a; int* nxt = b;
  cur[t] = v; __syncthreads();
  for (int off = 1; off < 256; off <<= 1) {
    nxt[t] = cur[t] + ((t >= off) ? cur[t - off] : 0);
    __syncthreads();
    int* tmp = cur; cur = nxt; nxt = tmp;
  }
  int excl = cur[t] - v + bsums[blockIdx.x];
  if (i < N_NODES) { row_start[i] = excl; cursor[i] = excl; }
  if (i == 0) row_start[N_NODES] = N_EDGES;
}

__global__ __launch_bounds__(256) void k_scatter_perm(const int* __restrict__ dst,
                                                      int* __restrict__ cursor,
                                                      int* __restrict__ perm) {
  int e = blockIdx.x * 256 + threadIdx.x;
  if (e < N_EDGES) {
    int pos = atomicAdd(&cursor[dst[e]], 1);
    perm[pos] = e;
  }
}

// ---------------------------------------------------------------------------
// MFMA edge-pass core.  Wave computes h[16 edges][128 ch] for group base e0.
__device__ __forceinline__ void load_W3_frags(const float* __restrict__ W,
                                              int lane, bf16x8* Bf) {
  const int c = lane & 15, q = lane >> 4;
#pragma unroll
  for (int nt = 0; nt < 8; ++nt) {
#pragma unroll
    for (int ks = 0; ks < 2; ++ks) {
      const float* wr = W + (size_t)(nt * 16 + c) * IN_DIM + 128 + ks * 32 + q * 8;
      f32x4 w0 = *(const f32x4*)wr;
      f32x4 w1 = *(const f32x4*)(wr + 4);
      bf16x8 f;
#pragma unroll
      for (int j = 0; j < 4; ++j) { f[j] = (__bf16)w0[j]; f[4 + j] = (__bf16)w1[j]; }
      Bf[nt * 2 + ks] = f;
    }
  }
}

__device__ __forceinline__ void compute_h(
    int e0, int lane, const float* __restrict__ e_feat,
    const int* __restrict__ src, const int* __restrict__ dst,
    const unsigned* __restrict__ P1p, const unsigned* __restrict__ P2p,
    const float* __restrict__ bn_, const bf16x8* Bf,
    float h[8][4], int dIdx[4]) {
  const int c = lane & 15, q = lane >> 4;
  const float* er = e_feat + (size_t)(e0 + c) * 64 + q * 8;
  f32x4 a0 = __builtin_nontemporal_load((const f32x4*)er);
  f32x4 a1 = __builtin_nontemporal_load((const f32x4*)(er + 4));
  f32x4 a2 = __builtin_nontemporal_load((const f32x4*)(er + 32));
  f32x4 a3 = __builtin_nontemporal_load((const f32x4*)(er + 36));
  int sIdx[4];
#pragma unroll
  for (int r = 0; r < 4; ++r) {
    dIdx[r] = dst[e0 + q * 4 + r];
    sIdx[r] = src[e0 + q * 4 + r];
  }
  bf16x8 A0, A1;
#pragma unroll
  for (int j = 0; j < 4; ++j) {
    A0[j] = (__bf16)a0[j]; A0[4 + j] = (__bf16)a1[j];
    A1[j] = (__bf16)a2[j]; A1[4 + j] = (__bf16)a3[j];
  }
  f32x4 acc[8];
#pragma unroll
  for (int nt = 0; nt < 8; ++nt) {
    acc[nt] = (f32x4){0.f, 0.f, 0.f, 0.f};
    acc[nt] = __builtin_amdgcn_mfma_f32_16x16x32_bf16(A0, Bf[nt * 2 + 0], acc[nt], 0, 0, 0);
    acc[nt] = __builtin_amdgcn_mfma_f32_16x16x32_bf16(A1, Bf[nt * 2 + 1], acc[nt], 0, 0, 0);
  }
#pragma unroll
  for (int r = 0; r < 4; ++r) {
    const unsigned* p1r = P1p + (size_t)dIdx[r] * 64 + c;
    const unsigned* p2r = P2p + (size_t)sIdx[r] * 64 + c;
#pragma unroll
    for (int ntp = 0; ntp < 4; ++ntp) {
      unsigned u1 = p1r[ntp * 16];
      unsigned u2 = p2r[ntp * 16];
      float lo = __uint_as_float(u1 << 16) + __uint_as_float(u2 << 16);
      float hi = __uint_as_float(u1 & 0xffff0000u) + __uint_as_float(u2 & 0xffff0000u);
      h[ntp][r]     = acc[ntp][r]     + lo + bn_[ntp];
      h[ntp + 4][r] = acc[ntp + 4][r] + hi + bn_[ntp + 4];
    }
  }
}

// ---------------------------------------------------------------------------
// Kernel 2: compute h, accumulate BN1 stats, materialize packed bf16 h.
__global__ __launch_bounds__(256, 4) void k_edge_h(
    const float* __restrict__ e_feat, const int* __restrict__ src,
    const int* __restrict__ dst, const float* __restrict__ W,
    const float* __restrict__ b, const unsigned* __restrict__ P1p,
    const unsigned* __restrict__ P2p, float* __restrict__ stats1,
    unsigned int* __restrict__ hbuf) {
  const int tid = threadIdx.x, lane = tid & 63, w = tid >> 6;
  const int c = lane & 15, q = lane >> 4;
  bf16x8 Bf[16];
  load_W3_frags(W, lane, Bf);
  float bn_[8];
#pragma unroll
  for (int nt = 0; nt < 8; ++nt) bn_[nt] = b[nt * 16 + c];
  float sums[8] = {0, 0, 0, 0, 0, 0, 0, 0};
  float sqs[8]  = {0, 0, 0, 0, 0, 0, 0, 0};
  for (int g0 = blockIdx.x * 64; g0 < N_EDGES; g0 += gridDim.x * 64) {
    const int e0 = g0 + w * 16;
    float h[8][4]; int dIdx[4];
    compute_h(e0, lane, e_feat, src, dst, P1p, P2p, bn_, Bf, h, dIdx);
#pragma unroll
    for (int nt = 0; nt < 8; ++nt)
#pragma unroll
      for (int r = 0; r < 4; ++r) {
        sums[nt] += h[nt][r];
        sqs[nt]  += h[nt][r] * h[nt][r];
      }
    if (hbuf) {
#pragma unroll
      for (int r = 0; r < 4; ++r) {
        unsigned int* hb = hbuf + (size_t)(e0 + q * 4 + r) * 64 + c;
#pragma unroll
        for (int nt = 0; nt < 4; ++nt)
          __builtin_nontemporal_store(pack_bf16x2(h[nt][r], h[nt + 4][r]), hb + nt * 16);
      }
    }
  }
  __shared__ float red[4][256];
#pragma unroll
  for (int nt = 0; nt < 8; ++nt) {
    float s = sums[nt]; s += __shfl_xor(s, 16, 64); s += __shfl_xor(s, 32, 64);
    float qv = sqs[nt]; qv += __shfl_xor(qv, 16, 64); qv += __shfl_xor(qv, 32, 64);
    if (lane < 16) { red[w][nt * 16 + lane] = s; red[w][128 + nt * 16 + lane] = qv; }
  }
  __syncthreads();
  float v = red[0][tid] + red[1][tid] + red[2][tid] + red[3][tid];
  unsafeAtomicAdd(&stats1[tid], v);
}

// Kernel 3: fold BN1 into per-channel affine.
__global__ void k_finalize1(const float* __restrict__ stats1,
                            const float* __restrict__ g1,
                            const float* __restrict__ beta1,
                            float* __restrict__ ss1) {
  int t = threadIdx.x;
  if (t < 128) {
    float inv_n = 1.f / (float)N_EDGES;
    float mu  = stats1[t] * inv_n;
    float var = stats1[128 + t] * inv_n - mu * mu;
    float sc  = g1[t] * rsqrtf(var + BN_EPS);
    ss1[t] = sc;
    ss1[128 + t] = beta1[t] - mu * sc;
  }
}

// ---------------------------------------------------------------------------
// Kernel 4: CSR gather. One wave per node: sum msgs over its edges (no
// atomics), write agg row once, and accumulate BN2 stats on the fly.
__global__ __launch_bounds__(256) void k_msg_gather(
    const unsigned int* __restrict__ hbuf, const int* __restrict__ perm,
    const int* __restrict__ row_start, const float* __restrict__ ss1,
    float* __restrict__ agg, float* __restrict__ stats2) {
  const int tid = threadIdx.x, lane = tid & 63, w = tid >> 6;
  const float sc_f = ss1[lane], sc_g = ss1[64 + lane];
  const float sh_f = ss1[128 + lane], sh_g = ss1[192 + lane];
  float ssum = 0.f, ssq = 0.f;
  for (int n = blockIdx.x * 4 + w; n < N_NODES; n += gridDim.x * 4) {
    const int beg = row_start[n], end = row_start[n + 1];
    float acc = 0.f;
    for (int j0 = beg; j0 < end; j0 += 64) {
      const int navail = min(64, end - j0);
      int e_l = (j0 + lane < end) ? perm[j0 + lane] : 0;
      int t = 0;
      for (; t + 4 <= navail; t += 4) {
        int e0 = __shfl(e_l, t + 0, 64), e1 = __shfl(e_l, t + 1, 64);
        int e2 = __shfl(e_l, t + 2, 64), e3 = __shfl(e_l, t + 3, 64);
        unsigned p0 = __builtin_nontemporal_load(hbuf + (size_t)e0 * 64 + lane);
        unsigned p1 = __builtin_nontemporal_load(hbuf + (size_t)e1 * 64 + lane);
        unsigned p2 = __builtin_nontemporal_load(hbuf + (size_t)e2 * 64 + lane);
        unsigned p3 = __builtin_nontemporal_load(hbuf + (size_t)e3 * 64 + lane);
        acc += msg_from_pack(p0, sc_f, sh_f, sc_g, sh_g);
        acc += msg_from_pack(p1, sc_f, sh_f, sc_g, sh_g);
        acc += msg_from_pack(p2, sc_f, sh_f, sc_g, sh_g);
        acc += msg_from_pack(p3, sc_f, sh_f, sc_g, sh_g);
      }
      for (; t < navail; ++t) {
        int e = __shfl(e_l, t, 64);
        unsigned p = __builtin_nontemporal_load(hbuf + (size_t)e * 64 + lane);
        acc += msg_from_pack(p, sc_f, sh_f, sc_g, sh_g);
      }
    }
    agg[(size_t)n * 64 + lane] = acc;
    ssum += acc; ssq += acc * acc;
  }
  __shared__ float ls[4][64], lq[4][64];
  ls[w][lane] = ssum; lq[w][lane] = ssq;
  __syncthreads();
  if (tid < 64) {
    unsafeAtomicAdd(&stats2[tid], ls[0][tid] + ls[1][tid] + ls[2][tid] + ls[3][tid]);
  } else if (tid < 128) {
    int t = tid - 64;
    unsafeAtomicAdd(&stats2[64 + t], lq[0][t] + lq[1][t] + lq[2][t] + lq[3][t]);
  }
}

// Fallback pass 2 (atomic scatter, recompute-free) if ws_size too small.
__global__ __launch_bounds__(256) void k_msg_scatter(
    const unsigned int* __restrict__ hbuf, const int* __restrict__ dst,
    const float* __restrict__ ss1, float* __restrict__ agg) {
  const int tid = threadIdx.x, lane = tid & 63, w = tid >> 6;
  const float sc_f = ss1[lane], sc_g = ss1[64 + lane];
  const float sh_f = ss1[128 + lane], sh_g = ss1[192 + lane];
  const int wave_id = blockIdx.x * 4 + w;
  const int n_waves = gridDim.x * 4;
  for (int e0 = wave_id * 8; e0 < N_EDGES; e0 += n_waves * 8) {
    unsigned int p[8]; int d[8];
#pragma unroll
    for (int j = 0; j < 8; ++j) {
      p[j] = __builtin_nontemporal_load(hbuf + (size_t)(e0 + j) * 64 + lane);
      d[j] = __builtin_amdgcn_readfirstlane(dst[e0 + j]);
    }
#pragma unroll
    for (int j = 0; j < 8; ++j)
      unsafeAtomicAdd(&agg[(size_t)d[j] * 64 + lane],
                      msg_from_pack(p[j], sc_f, sh_f, sc_g, sh_g));
  }
}

// Kernel 5 (fallback only): BN2 stats over agg rows.
__global__ __launch_bounds__(256) void k_agg_stats(const float* __restrict__ agg,
                                                   float* __restrict__ stats2) {
  const int tid = threadIdx.x;
  const int c = tid & 63, w = tid >> 6;
  float s = 0.f, sq = 0.f;
  for (int r = blockIdx.x * 4 + w; r < N_NODES; r += gridDim.x * 4) {
    float v = agg[(size_t)r * 64 + c];
    s += v; sq += v * v;
  }
  __shared__ float ws_[4][64], wq_[4][64];
  ws_[w][c] = s; wq_[w][c] = sq;
  __syncthreads();
  if (tid < 64) {
    unsafeAtomicAdd(&stats2[tid], ws_[0][tid] + ws_[1][tid] + ws_[2][tid] + ws_[3][tid]);
  } else if (tid < 128) {
    int t = tid - 64;
    unsafeAtomicAdd(&stats2[64 + t], wq_[0][t] + wq_[1][t] + wq_[2][t] + wq_[3][t]);
  }
}

__global__ void k_finalize2(const float* __restrict__ stats2,
                            const float* __restrict__ g2,
                            const float* __restrict__ beta2,
                            float* __restrict__ ss2) {
  int t = threadIdx.x;
  if (t < 64) {
    float inv_n = 1.f / (float)N_NODES;
    float mu  = stats2[t] * inv_n;
    float var = stats2[64 + t] * inv_n - mu * mu;
    float sc  = g2[t] * rsqrtf(var + BN_EPS);
    ss2[t] = sc;
    ss2[64 + t] = beta2[t] - mu * sc;
  }
}

// Kernel 7: out = softplus(BN2(agg) + n_feat), float4-vectorized.
__global__ __launch_bounds__(256) void k_output(const float* __restrict__ agg,
                                                const float* __restrict__ n_feat,
                                                const float* __restrict__ ss2,
                                                float* __restrict__ out) {
  int i = blockIdx.x * 256 + threadIdx.x;
  if (i >= N_NODES * 16) return;
  int cb = (i & 15) * 4;
  float4 a = ((const float4*)agg)[i];
  float4 x = ((const float4*)n_feat)[i];
  float4 r;
  r.x = fast_softplus(a.x * ss2[cb + 0] + ss2[64 + cb + 0] + x.x);
  r.y = fast_softplus(a.y * ss2[cb + 1] + ss2[64 + cb + 1] + x.y);
  r.z = fast_softplus(a.z * ss2[cb + 2] + ss2[64 + cb + 2] + x.z);
  r.w = fast_softplus(a.w * ss2[cb + 3] + ss2[64 + cb + 3] + x.w);
  ((float4*)out)[i] = r;
}

extern "C" void kernel_launch(void* const* d_in, const int* in_sizes, int n_in,
                              void* d_out, int out_size, void* d_ws, size_t ws_size,
                              hipStream_t stream) {
  const float* n_feat = (const float*)d_in[0];
  const float* e_feat = (const float*)d_in[1];
  const int*   src    = (const int*)d_in[2];
  const int*   dst    = (const int*)d_in[3];
  const float* W      = (const float*)d_in[4];
  const float* b      = (const float*)d_in[5];
  const float* g1     = (const float*)d_in[6];
  const float* beta1  = (const float*)d_in[7];
  const float* g2     = (const float*)d_in[8];
  const float* beta2  = (const float*)d_in[9];

  unsigned* ws  = (unsigned*)d_ws;
  unsigned* P1p = ws;
  unsigned* P2p = ws + OFF_P2P;
  float* agg    = (float*)(ws + OFF_AGG);
  float* stats1 = (float*)(ws + OFF_STATS1);
  float* ss1    = stats1 + 256;
  float* stats2 = ss1 + 256;
  float* ss2    = stats2 + 128;
  int* row_start = (int*)(ws + OFF_ROWS);
  int* cursor    = (int*)(ws + OFF_CURSOR);
  int* bsums     = (int*)(ws + OFF_BSUMS);
  int* perm      = (int*)(ws + OFF_PERM);
  unsigned int* hbuf = ws + OFF_HBUF;
  float* out    = (float*)d_out;

  const bool have_full = ws_size >= WS_WORDS_NEEDED * 4;

  hipMemsetAsync(stats1, 0, 768 * sizeof(float), stream);

  k_precompute<<<1024, 256, 0, stream>>>(n_feat, W, P1p, P2p);
  if (have_full) {
    // CSR build (independent of edge compute, tiny L2-resident kernels)
    hipMemsetAsync(cursor, 0, N_NODES * sizeof(int), stream);
    k_hist<<<(N_EDGES + 255) / 256, 256, 0, stream>>>(dst, cursor);
    k_scan1<<<SCAN_BLOCKS, 256, 0, stream>>>(cursor, bsums);
    k_scan2<<<1, 256, 0, stream>>>(bsums);
    k_scan3<<<SCAN_BLOCKS, 256, 0, stream>>>(bsums, row_start, cursor);
    k_scatter_perm<<<(N_EDGES + 255) / 256, 256, 0, stream>>>(dst, cursor, perm);

    k_edge_h<<<2048, 256, 0, stream>>>(e_feat, src, dst, W, b, P1p, P2p, stats1, hbuf);
    k_finalize1<<<1, 128, 0, stream>>>(stats1, g1, beta1, ss1);
    k_msg_gather<<<2048, 256, 0, stream>>>(hbuf, perm, row_start, ss1, agg, stats2);
  } else {
    hipMemsetAsync(agg, 0, (size_t)N_NODES * 64 * sizeof(float), stream);
    k_edge_h<<<2048, 256, 0, stream>>>(e_feat, src, dst, W, b, P1p, P2p, stats1, hbuf);
    k_finalize1<<<1, 128, 0, stream>>>(stats1, g1, beta1, ss1);
    k_msg_scatter<<<2048, 256, 0, stream>>>(hbuf, dst, ss1, agg);
    k_agg_stats<<<512, 256, 0, stream>>>(agg, stats2);
  }
  k_finalize2<<<1, 64, 0, stream>>>(stats2, g2, beta2, ss2);
  k_output<<<3125, 256, 0, stream>>>(agg, n_feat, ss2, out);
}

// Round 6
// 676.715 us; speedup vs baseline: 1.0724x; 1.0724x over previous
//
#include <hip/hip_runtime.h>
#include <math.h>

// Problem constants (from reference)
#define N_NODES 50000
#define N_EDGES 800000
#define IN_DIM  192      // 2*O + ED
#define BN_EPS  1e-5f

// Workspace layout (4-byte word offsets):
//   P1p    [N,64]  uint @ 0          packed bf16x2 {chan n, chan n+64} of n_feat@W1^T
//   P2p    [N,64]  uint @ 3,200,000  same for W2^T
//   agg    [N,64]  f32  @ 6,400,000
//   stats  [768]   f32  @ 9,600,000  stats1[256], ss1[256], stats2[128], ss2[128]
//   rows   [N+1]   int  @ 9,601,024  CSR row_start
//   cursor [N]     int  @ 9,651,032
//   bsums  [256]   int  @ 9,701,040
//   perm   [E]     int  @ 9,701,296  dst-sorted edge ids
//   dsts   [E]     int  @ 10,501,296 dst in sorted order
//   srcs   [E]     int  @ 11,301,296 src in sorted order
//   hbuf   [E,64]  uint @ 12,101,296 packed bf16x2 {filt,core}, dst-sorted rows
#define OFF_P2P    3200000
#define OFF_AGG    6400000
#define OFF_STATS1 9600000
#define OFF_ROWS   9601024
#define OFF_CURSOR 9651032
#define OFF_BSUMS  9701040
#define OFF_PERM   9701296
#define OFF_DSTS   10501296
#define OFF_SRCS   11301296
#define OFF_HBUF   12101296
#define WS_WORDS_NEEDED (OFF_HBUF + (size_t)N_EDGES * 64)
#define SCAN_BLOCKS ((N_NODES + 255) / 256)   // 196

typedef __bf16 bf16x8 __attribute__((ext_vector_type(8)));
typedef __bf16 bf16x2 __attribute__((ext_vector_type(2)));
typedef float  f32x4  __attribute__((ext_vector_type(4)));

__device__ __forceinline__ unsigned pack_bf16x2(float lo, float hi) {
  union { bf16x2 v; unsigned u; } pk;
  pk.v[0] = (__bf16)lo; pk.v[1] = (__bf16)hi;
  return pk.u;
}
__device__ __forceinline__ float fast_sigmoid(float f) {
  return __builtin_amdgcn_rcpf(1.f + __expf(-f));
}
__device__ __forceinline__ float fast_softplus(float g) {
  return fmaxf(g, 0.f) + __logf(1.f + __expf(-fabsf(g)));
}
__device__ __forceinline__ float msg_from_pack(unsigned p, float sc_f, float sh_f,
                                               float sc_g, float sh_g) {
  float f = __uint_as_float(p << 16)         * sc_f + sh_f;
  float g = __uint_as_float(p & 0xffff0000u) * sc_g + sh_g;
  return fast_sigmoid(f) * fast_softplus(g);
}

// ---------------------------------------------------------------------------
// Kernel 1: P1p[n][o] = pack(bf16(n_feat[n]·W[o][0:64]), bf16(n_feat[n]·W[o+64][0:64]))
__global__ __launch_bounds__(256) void k_precompute(
    const float* __restrict__ n_feat, const float* __restrict__ W,
    unsigned* __restrict__ P1p, unsigned* __restrict__ P2p) {
  const int tid = threadIdx.x;
  const int o   = tid & 63;
  const int sel = tid >> 6;                 // 0..3
  const int ch  = o + (sel & 1) * 64;
  const int kb  = (sel & 2) ? 64 : 0;
  float4 wreg[16];
  const float* wrow = W + (size_t)ch * IN_DIM + kb;
#pragma unroll
  for (int i = 0; i < 16; ++i) wreg[i] = *(const float4*)(wrow + i * 4);
  __shared__ float xrow[4][64];
  __shared__ float accbuf[4][4][64];        // [sel][r][o]
  for (int r0 = blockIdx.x * 4; r0 < N_NODES; r0 += gridDim.x * 4) {
    xrow[tid >> 6][tid & 63] = n_feat[(size_t)(r0 + (tid >> 6)) * 64 + (tid & 63)];
    __syncthreads();
    float acc[4] = {0.f, 0.f, 0.f, 0.f};
#pragma unroll
    for (int kk = 0; kk < 16; ++kk) {
      float4 wv = wreg[kk];
#pragma unroll
      for (int r = 0; r < 4; ++r) {
        float4 xv = *(const float4*)&xrow[r][kk * 4];
        acc[r] += wv.x * xv.x + wv.y * xv.y + wv.z * xv.z + wv.w * xv.w;
      }
    }
#pragma unroll
    for (int r = 0; r < 4; ++r) accbuf[sel][r][o] = acc[r];
    __syncthreads();
    const size_t rr = (size_t)(r0 + sel) * 64 + o;
    P1p[rr] = pack_bf16x2(accbuf[0][sel][o], accbuf[1][sel][o]);
    P2p[rr] = pack_bf16x2(accbuf[2][sel][o], accbuf[3][sel][o]);
    __syncthreads();
  }
}

// ---------------------------------------------------------------------------
// CSR build: histogram -> exclusive scan -> scatter (perm + sorted dst/src).
__global__ __launch_bounds__(256) void k_hist(const int* __restrict__ dst,
                                              int* __restrict__ counts) {
  int e = blockIdx.x * 256 + threadIdx.x;
  if (e < N_EDGES) atomicAdd(&counts[dst[e]], 1);
}

__global__ __launch_bounds__(256) void k_scan1(const int* __restrict__ counts,
                                               int* __restrict__ bsums) {
  __shared__ int red[256];
  int i = blockIdx.x * 256 + threadIdx.x;
  red[threadIdx.x] = (i < N_NODES) ? counts[i] : 0;
  __syncthreads();
  for (int s = 128; s > 0; s >>= 1) {
    if (threadIdx.x < s) red[threadIdx.x] += red[threadIdx.x + s];
    __syncthreads();
  }
  if (threadIdx.x == 0) bsums[blockIdx.x] = red[0];
}

__global__ __launch_bounds__(256) void k_scan2(int* __restrict__ bsums) {
  __shared__ int a[256], b[256];
  int t = threadIdx.x;
  int v = (t < SCAN_BLOCKS) ? bsums[t] : 0;
  int* cur = a; int* nxt = b;
  cur[t] = v; __syncthreads();
  for (int off = 1; off < 256; off <<= 1) {
    nxt[t] = cur[t] + ((t >= off) ? cur[t - off] : 0);
    __syncthreads();
    int* tmp = cur; cur = nxt; nxt = tmp;
  }
  if (t < SCAN_BLOCKS) bsums[t] = cur[t] - v;   // exclusive
}

__global__ __launch_bounds__(256) void k_scan3(const int* __restrict__ bsums,
                                               int* __restrict__ row_start,
                                               int* __restrict__ cursor) {
  __shared__ int a[256], b[256];
  int i = blockIdx.x * 256 + threadIdx.x;
  int t = threadIdx.x;
  int v = (i < N_NODES) ? cursor[i] : 0;        // cursor holds counts
  int* cur = a; int* nxt = b;
  cur[t] = v; __syncthreads();
  for (int off = 1; off < 256; off <<= 1) {
    nxt[t] = cur[t] + ((t >= off) ? cur[t - off] : 0);
    __syncthreads();
    int* tmp = cur; cur = nxt; nxt = tmp;
  }
  int excl = cur[t] - v + bsums[blockIdx.x];
  if (i < N_NODES) { row_start[i] = excl; cursor[i] = excl; }
  if (i == 0) row_start[N_NODES] = N_EDGES;
}

__global__ __launch_bounds__(256) void k_scatter_perm(
    const int* __restrict__ dst, const int* __restrict__ src,
    int* __restrict__ cursor, int* __restrict__ perm,
    int* __restrict__ dsts, int* __restrict__ srcs) {
  int e = blockIdx.x * 256 + threadIdx.x;
  if (e < N_EDGES) {
    int d = dst[e];
    int pos = atomicAdd(&cursor[d], 1);
    perm[pos] = e;
    dsts[pos] = d;
    srcs[pos] = src[e];
  }
}

// ---------------------------------------------------------------------------
// Kernel 2: edge pass in (optionally) dst-sorted order.  Wave computes
// h[16 edges][128 ch]; Q via 16x16x32 bf16 MFMA; accumulates BN1 stats;
// writes packed bf16x2 {filt,core} rows to hbuf at the processing index
// (= sorted position when perm != null).
//   A-frag row for lane: edge perm[e0 + (lane&15)]   (gathered 256B rows)
//   dst/src indices: dsts/srcs[e0 + ...]             (sequential)
__global__ __launch_bounds__(256, 3) void k_edge_h(
    const float* __restrict__ e_feat, const int* __restrict__ perm,
    const int* __restrict__ dsts, const int* __restrict__ srcs,
    const float* __restrict__ W, const float* __restrict__ b,
    const unsigned* __restrict__ P1p, const unsigned* __restrict__ P2p,
    float* __restrict__ stats1, unsigned int* __restrict__ hbuf) {
  const int tid = threadIdx.x, lane = tid & 63, w = tid >> 6;
  const int c = lane & 15, q = lane >> 4;
  // B fragments: W3 rows nt*16+c, bf16
  bf16x8 Bf[16];
#pragma unroll
  for (int nt = 0; nt < 8; ++nt) {
#pragma unroll
    for (int ks = 0; ks < 2; ++ks) {
      const float* wr = W + (size_t)(nt * 16 + c) * IN_DIM + 128 + ks * 32 + q * 8;
      f32x4 w0 = *(const f32x4*)wr;
      f32x4 w1 = *(const f32x4*)(wr + 4);
      bf16x8 f;
#pragma unroll
      for (int j = 0; j < 4; ++j) { f[j] = (__bf16)w0[j]; f[4 + j] = (__bf16)w1[j]; }
      Bf[nt * 2 + ks] = f;
    }
  }
  float bn_[8];
#pragma unroll
  for (int nt = 0; nt < 8; ++nt) bn_[nt] = b[nt * 16 + c];
  float sums[8] = {0, 0, 0, 0, 0, 0, 0, 0};
  float sqs[8]  = {0, 0, 0, 0, 0, 0, 0, 0};
  for (int g0 = blockIdx.x * 64; g0 < N_EDGES; g0 += gridDim.x * 64) {
    const int e0 = g0 + w * 16;
    // A fragment: lane's e_feat row (gathered when sorted)
    const int arow = perm ? perm[e0 + c] : (e0 + c);
    const float* er = e_feat + (size_t)arow * 64 + q * 8;
    f32x4 a0 = __builtin_nontemporal_load((const f32x4*)er);
    f32x4 a1 = __builtin_nontemporal_load((const f32x4*)(er + 4));
    f32x4 a2 = __builtin_nontemporal_load((const f32x4*)(er + 32));
    f32x4 a3 = __builtin_nontemporal_load((const f32x4*)(er + 36));
    int dIdx[4], sIdx[4];
#pragma unroll
    for (int r = 0; r < 4; ++r) {
      dIdx[r] = dsts[e0 + q * 4 + r];
      sIdx[r] = srcs[e0 + q * 4 + r];
    }
    bf16x8 A0, A1;
#pragma unroll
    for (int j = 0; j < 4; ++j) {
      A0[j] = (__bf16)a0[j]; A0[4 + j] = (__bf16)a1[j];
      A1[j] = (__bf16)a2[j]; A1[4 + j] = (__bf16)a3[j];
    }
    f32x4 acc[8];
#pragma unroll
    for (int nt = 0; nt < 8; ++nt) {
      acc[nt] = (f32x4){0.f, 0.f, 0.f, 0.f};
      acc[nt] = __builtin_amdgcn_mfma_f32_16x16x32_bf16(A0, Bf[nt * 2 + 0], acc[nt], 0, 0, 0);
      acc[nt] = __builtin_amdgcn_mfma_f32_16x16x32_bf16(A1, Bf[nt * 2 + 1], acc[nt], 0, 0, 0);
    }
    float h[8][4];
#pragma unroll
    for (int r = 0; r < 4; ++r) {
      const unsigned* p1r = P1p + (size_t)dIdx[r] * 64 + c;
      const unsigned* p2r = P2p + (size_t)sIdx[r] * 64 + c;
#pragma unroll
      for (int ntp = 0; ntp < 4; ++ntp) {
        unsigned u1 = p1r[ntp * 16];
        unsigned u2 = p2r[ntp * 16];
        float lo = __uint_as_float(u1 << 16) + __uint_as_float(u2 << 16);
        float hi = __uint_as_float(u1 & 0xffff0000u) + __uint_as_float(u2 & 0xffff0000u);
        h[ntp][r]     = acc[ntp][r]     + lo + bn_[ntp];
        h[ntp + 4][r] = acc[ntp + 4][r] + hi + bn_[ntp + 4];
      }
    }
#pragma unroll
    for (int nt = 0; nt < 8; ++nt)
#pragma unroll
      for (int r = 0; r < 4; ++r) {
        sums[nt] += h[nt][r];
        sqs[nt]  += h[nt][r] * h[nt][r];
      }
#pragma unroll
    for (int r = 0; r < 4; ++r) {
      unsigned int* hb = hbuf + (size_t)(e0 + q * 4 + r) * 64 + c;
#pragma unroll
      for (int nt = 0; nt < 4; ++nt)
        __builtin_nontemporal_store(pack_bf16x2(h[nt][r], h[nt + 4][r]), hb + nt * 16);
    }
  }
  __shared__ float red[4][256];
#pragma unroll
  for (int nt = 0; nt < 8; ++nt) {
    float s = sums[nt]; s += __shfl_xor(s, 16, 64); s += __shfl_xor(s, 32, 64);
    float qv = sqs[nt]; qv += __shfl_xor(qv, 16, 64); qv += __shfl_xor(qv, 32, 64);
    if (lane < 16) { red[w][nt * 16 + lane] = s; red[w][128 + nt * 16 + lane] = qv; }
  }
  __syncthreads();
  float v = red[0][tid] + red[1][tid] + red[2][tid] + red[3][tid];
  unsafeAtomicAdd(&stats1[tid], v);
}

// Kernel 3: fold BN1 into per-channel affine.
__global__ void k_finalize1(const float* __restrict__ stats1,
                            const float* __restrict__ g1,
                            const float* __restrict__ beta1,
                            float* __restrict__ ss1) {
  int t = threadIdx.x;
  if (t < 128) {
    float inv_n = 1.f / (float)N_EDGES;
    float mu  = stats1[t] * inv_n;
    float var = stats1[128 + t] * inv_n - mu * mu;
    float sc  = g1[t] * rsqrtf(var + BN_EPS);
    ss1[t] = sc;
    ss1[128 + t] = beta1[t] - mu * sc;
  }
}

// ---------------------------------------------------------------------------
// Kernel 4: streaming gather over dst-sorted hbuf. One wave per node reads
// its contiguous row range [row_start[n], row_start[n+1]), no atomics on agg.
// BN2 stats accumulated on the fly.
__global__ __launch_bounds__(256) void k_msg_gather(
    const unsigned int* __restrict__ hbuf, const int* __restrict__ row_start,
    const float* __restrict__ ss1, float* __restrict__ agg,
    float* __restrict__ stats2) {
  const int tid = threadIdx.x, lane = tid & 63, w = tid >> 6;
  const float sc_f = ss1[lane], sc_g = ss1[64 + lane];
  const float sh_f = ss1[128 + lane], sh_g = ss1[192 + lane];
  float ssum = 0.f, ssq = 0.f;
  for (int n = blockIdx.x * 4 + w; n < N_NODES; n += gridDim.x * 4) {
    const int beg = row_start[n], end = row_start[n + 1];
    float acc = 0.f;
    int j = beg;
    for (; j + 4 <= end; j += 4) {
      unsigned p0 = __builtin_nontemporal_load(hbuf + (size_t)(j + 0) * 64 + lane);
      unsigned p1 = __builtin_nontemporal_load(hbuf + (size_t)(j + 1) * 64 + lane);
      unsigned p2 = __builtin_nontemporal_load(hbuf + (size_t)(j + 2) * 64 + lane);
      unsigned p3 = __builtin_nontemporal_load(hbuf + (size_t)(j + 3) * 64 + lane);
      acc += msg_from_pack(p0, sc_f, sh_f, sc_g, sh_g);
      acc += msg_from_pack(p1, sc_f, sh_f, sc_g, sh_g);
      acc += msg_from_pack(p2, sc_f, sh_f, sc_g, sh_g);
      acc += msg_from_pack(p3, sc_f, sh_f, sc_g, sh_g);
    }
    for (; j < end; ++j) {
      unsigned p = __builtin_nontemporal_load(hbuf + (size_t)j * 64 + lane);
      acc += msg_from_pack(p, sc_f, sh_f, sc_g, sh_g);
    }
    agg[(size_t)n * 64 + lane] = acc;
    ssum += acc; ssq += acc * acc;
  }
  __shared__ float ls[4][64], lq[4][64];
  ls[w][lane] = ssum; lq[w][lane] = ssq;
  __syncthreads();
  if (tid < 64) {
    unsafeAtomicAdd(&stats2[tid], ls[0][tid] + ls[1][tid] + ls[2][tid] + ls[3][tid]);
  } else if (tid < 128) {
    int t = tid - 64;
    unsafeAtomicAdd(&stats2[64 + t], lq[0][t] + lq[1][t] + lq[2][t] + lq[3][t]);
  }
}

// Fallback pass 2 (atomic scatter over edge-ordered hbuf) if ws too small.
__global__ __launch_bounds__(256) void k_msg_scatter(
    const unsigned int* __restrict__ hbuf, const int* __restrict__ dst,
    const float* __restrict__ ss1, float* __restrict__ agg) {
  const int tid = threadIdx.x, lane = tid & 63, w = tid >> 6;
  const float sc_f = ss1[lane], sc_g = ss1[64 + lane];
  const float sh_f = ss1[128 + lane], sh_g = ss1[192 + lane];
  const int wave_id = blockIdx.x * 4 + w;
  const int n_waves = gridDim.x * 4;
  for (int e0 = wave_id * 8; e0 < N_EDGES; e0 += n_waves * 8) {
    unsigned int p[8]; int d[8];
#pragma unroll
    for (int j = 0; j < 8; ++j) {
      p[j] = __builtin_nontemporal_load(hbuf + (size_t)(e0 + j) * 64 + lane);
      d[j] = __builtin_amdgcn_readfirstlane(dst[e0 + j]);
    }
#pragma unroll
    for (int j = 0; j < 8; ++j)
      unsafeAtomicAdd(&agg[(size_t)d[j] * 64 + lane],
                      msg_from_pack(p[j], sc_f, sh_f, sc_g, sh_g));
  }
}

// Kernel 5 (fallback only): BN2 stats over agg rows.
__global__ __launch_bounds__(256) void k_agg_stats(const float* __restrict__ agg,
                                                   float* __restrict__ stats2) {
  const int tid = threadIdx.x;
  const int c = tid & 63, w = tid >> 6;
  float s = 0.f, sq = 0.f;
  for (int r = blockIdx.x * 4 + w; r < N_NODES; r += gridDim.x * 4) {
    float v = agg[(size_t)r * 64 + c];
    s += v; sq += v * v;
  }
  __shared__ float ws_[4][64], wq_[4][64];
  ws_[w][c] = s; wq_[w][c] = sq;
  __syncthreads();
  if (tid < 64) {
    unsafeAtomicAdd(&stats2[tid], ws_[0][tid] + ws_[1][tid] + ws_[2][tid] + ws_[3][tid]);
  } else if (tid < 128) {
    int t = tid - 64;
    unsafeAtomicAdd(&stats2[64 + t], wq_[0][t] + wq_[1][t] + wq_[2][t] + wq_[3][t]);
  }
}

__global__ void k_finalize2(const float* __restrict__ stats2,
                            const float* __restrict__ g2,
                            const float* __restrict__ beta2,
                            float* __restrict__ ss2) {
  int t = threadIdx.x;
  if (t < 64) {
    float inv_n = 1.f / (float)N_NODES;
    float mu  = stats2[t] * inv_n;
    float var = stats2[64 + t] * inv_n - mu * mu;
    float sc  = g2[t] * rsqrtf(var + BN_EPS);
    ss2[t] = sc;
    ss2[64 + t] = beta2[t] - mu * sc;
  }
}

// Kernel 7: out = softplus(BN2(agg) + n_feat), float4-vectorized.
__global__ __launch_bounds__(256) void k_output(const float* __restrict__ agg,
                                                const float* __restrict__ n_feat,
                                                const float* __restrict__ ss2,
                                                float* __restrict__ out) {
  int i = blockIdx.x * 256 + threadIdx.x;
  if (i >= N_NODES * 16) return;
  int cb = (i & 15) * 4;
  float4 a = ((const float4*)agg)[i];
  float4 x = ((const float4*)n_feat)[i];
  float4 r;
  r.x = fast_softplus(a.x * ss2[cb + 0] + ss2[64 + cb + 0] + x.x);
  r.y = fast_softplus(a.y * ss2[cb + 1] + ss2[64 + cb + 1] + x.y);
  r.z = fast_softplus(a.z * ss2[cb + 2] + ss2[64 + cb + 2] + x.z);
  r.w = fast_softplus(a.w * ss2[cb + 3] + ss2[64 + cb + 3] + x.w);
  ((float4*)out)[i] = r;
}

extern "C" void kernel_launch(void* const* d_in, const int* in_sizes, int n_in,
                              void* d_out, int out_size, void* d_ws, size_t ws_size,
                              hipStream_t stream) {
  const float* n_feat = (const float*)d_in[0];
  const float* e_feat = (const float*)d_in[1];
  const int*   src    = (const int*)d_in[2];
  const int*   dst    = (const int*)d_in[3];
  const float* W      = (const float*)d_in[4];
  const float* b      = (const float*)d_in[5];
  const float* g1     = (const float*)d_in[6];
  const float* beta1  = (const float*)d_in[7];
  const float* g2     = (const float*)d_in[8];
  const float* beta2  = (const float*)d_in[9];

  unsigned* ws  = (unsigned*)d_ws;
  unsigned* P1p = ws;
  unsigned* P2p = ws + OFF_P2P;
  float* agg    = (float*)(ws + OFF_AGG);
  float* stats1 = (float*)(ws + OFF_STATS1);
  float* ss1    = stats1 + 256;
  float* stats2 = ss1 + 256;
  float* ss2    = stats2 + 128;
  int* row_start = (int*)(ws + OFF_ROWS);
  int* cursor    = (int*)(ws + OFF_CURSOR);
  int* bsums     = (int*)(ws + OFF_BSUMS);
  int* perm      = (int*)(ws + OFF_PERM);
  int* dsts      = (int*)(ws + OFF_DSTS);
  int* srcs      = (int*)(ws + OFF_SRCS);
  unsigned int* hbuf = ws + OFF_HBUF;
  float* out    = (float*)d_out;

  const bool have_full = ws_size >= WS_WORDS_NEEDED * 4;

  hipMemsetAsync(stats1, 0, 768 * sizeof(float), stream);

  if (have_full) {
    // CSR build
    hipMemsetAsync(cursor, 0, N_NODES * sizeof(int), stream);
    k_hist<<<(N_EDGES + 255) / 256, 256, 0, stream>>>(dst, cursor);
    k_scan1<<<SCAN_BLOCKS, 256, 0, stream>>>(cursor, bsums);
    k_scan2<<<1, 256, 0, stream>>>(bsums);
    k_scan3<<<SCAN_BLOCKS, 256, 0, stream>>>(bsums, row_start, cursor);
    k_scatter_perm<<<(N_EDGES + 255) / 256, 256, 0, stream>>>(dst, src, cursor,
                                                              perm, dsts, srcs);
    k_precompute<<<1024, 256, 0, stream>>>(n_feat, W, P1p, P2p);
    k_edge_h<<<2048, 256, 0, stream>>>(e_feat, perm, dsts, srcs, W, b, P1p, P2p,
                                       stats1, hbuf);
    k_finalize1<<<1, 128, 0, stream>>>(stats1, g1, beta1, ss1);
    k_msg_gather<<<2048, 256, 0, stream>>>(hbuf, row_start, ss1, agg, stats2);
  } else {
    hipMemsetAsync(agg, 0, (size_t)N_NODES * 64 * sizeof(float), stream);
    k_precompute<<<1024, 256, 0, stream>>>(n_feat, W, P1p, P2p);
    k_edge_h<<<2048, 256, 0, stream>>>(e_feat, nullptr, dst, src, W, b, P1p, P2p,
                                       stats1, hbuf);
    k_finalize1<<<1, 128, 0, stream>>>(stats1, g1, beta1, ss1);
    k_msg_scatter<<<2048, 256, 0, stream>>>(hbuf, dst, ss1, agg);
    k_agg_stats<<<512, 256, 0, stream>>>(agg, stats2);
  }
  k_finalize2<<<1, 64, 0, stream>>>(stats2, g2, beta2, ss2);
  k_output<<<3125, 256, 0, stream>>>(agg, n_feat, ss2, out);
}